// Round 12
// baseline (238.326 us; speedup 1.0000x reference)
//
#include <hip/hip_runtime.h>
#include <math.h>

// Problem constants
constexpr int Bsz  = 64;
constexpr int Tseq = 256;
constexpr int Cdim = 384;
constexpr int Hh   = 6;
constexpr int HSd  = 64;
constexpr int Mrows = Bsz * Tseq;        // 16384
constexpr int Cffn  = 4 * Cdim;          // 1536
constexpr int Nqkv  = 3 * Cdim;          // 1152

typedef __attribute__((ext_vector_type(8))) short short8;  // 8 bf16 = 4 VGPRs
typedef __attribute__((ext_vector_type(4))) float f32x4;

// fp32 -> bf16 round-to-nearest-even
__device__ __forceinline__ ushort f2bf(float x) {
  union { float f; uint u; } a; a.f = x;
  uint r = a.u + 0x7fffu + ((a.u >> 16) & 1u);
  return (ushort)(r >> 16);
}
__device__ __forceinline__ float bf2f(ushort u) {
  union { uint u; float f; } a; a.u = ((uint)u) << 16;
  return a.f;
}
// Pack 2 f32 -> 2 bf16 (RNE) in one instruction (T12 recipe, no builtin).
__device__ __forceinline__ uint pk_bf16(float lo, float hi) {
  uint r;
  asm("v_cvt_pk_bf16_f32 %0, %1, %2" : "=v"(r) : "v"(lo), "v"(hi));
  return r;
}

// Fast GELU (tanh form): ~3e-4 max error vs exact-erf, ~8 VALU ops vs ~25.
__device__ __forceinline__ float gelu_fast(float x) {
  float t = x * x;
  float u = x * fmaf(0.044715f, t, 1.0f);
  float e = fminf(1.5957691216f * u, 80.f);
  float z = __expf(e);
  return x * (z / (1.0f + z));
}

// ---------------------------------------------------------------------------
// Fused prep + LN1, one launch (R10 win). Blocks 0..1727 = 32x32 transpose
// tiles; 1728..1732 bias concat; 1733..5828 = LN1 rows (4 rows per block).
// pih(c) = (c & ~63) + (c&15)*4 + ((c>>4)&3) k-permutation applied to
// Wproj k-axis (matches QKV EPI=3 store) and W2 k-axis (matches FFN1 EPI=2
// store). Per-64-block only (row-wide perm broke store coalescing, R5).
// ---------------------------------------------------------------------------
__global__ __launch_bounds__(256) void prep_kernel(
    const float* __restrict__ Wq, const float* __restrict__ Wk,
    const float* __restrict__ Wv, const float* __restrict__ Wproj,
    const float* __restrict__ W1, const float* __restrict__ W2,
    const float* __restrict__ bq, const float* __restrict__ bk,
    const float* __restrict__ bv,
    const float* __restrict__ x, const float* __restrict__ ln1_w,
    const float* __restrict__ ln1_b,
    ushort* __restrict__ WqkvT, ushort* __restrict__ WprojT,
    ushort* __restrict__ W1T, ushort* __restrict__ W2T,
    float* __restrict__ bqkv, ushort* __restrict__ hOut) {
  const int bid = blockIdx.x;
  if (bid >= 1733) {  // -------- LN1: 4 rows per block --------
    const int row  = (bid - 1733) * 4 + (threadIdx.x >> 6);
    const int lane = threadIdx.x & 63;
    if (row >= Mrows) return;
    const float* xr = x + (size_t)row * Cdim;
    float v[6];
    float s = 0.f;
#pragma unroll
    for (int i = 0; i < 6; ++i) { v[i] = xr[lane + 64 * i]; s += v[i]; }
#pragma unroll
    for (int off = 32; off > 0; off >>= 1) s += __shfl_xor(s, off, 64);
    float mean = s * (1.f / Cdim);
    float sq = 0.f;
#pragma unroll
    for (int i = 0; i < 6; ++i) { float d = v[i] - mean; sq += d * d; }
#pragma unroll
    for (int off = 32; off > 0; off >>= 1) sq += __shfl_xor(sq, off, 64);
    float rstd = rsqrtf(sq * (1.f / Cdim) + 1e-5f);
    ushort* orow = hOut + (size_t)row * Cdim;
#pragma unroll
    for (int i = 0; i < 6; ++i) {
      int c = lane + 64 * i;
      orow[c] = f2bf((v[i] - mean) * rstd * ln1_w[c] + ln1_b[c]);
    }
    return;
  }
  if (bid >= 1728) {  // bias concat
    int i = (bid - 1728) * 256 + threadIdx.x;
    if (i < Nqkv)
      bqkv[i] = (i < 384) ? bq[i] : (i < 768) ? bk[i - 384] : bv[i - 768];
    return;
  }
  const int tx = threadIdx.x & 31, ty = threadIdx.x >> 5;  // 32 x 8
  const float* src; ushort* dst; int R, S, r0, s0, perm = 0;
  if (bid < 432) {           // Wq/Wk/Wv: [6][384][64] each -> rows of WqkvT
    int which = bid / 144, rem = bid % 144;
    const float* W = (which == 0) ? Wq : (which == 1) ? Wk : Wv;
    int bz = rem / 24, t = rem % 24;
    R = 384; S = 64;
    src = W + (size_t)bz * R * S;
    dst = WqkvT + (size_t)which * 384 * 384 + (size_t)bz * R * S;
    r0 = (t >> 1) * 32; s0 = (t & 1) * 32;
  } else if (bid < 576) {    // Wproj 384x384 (k-axis pih per 64-block)
    int rem = bid - 432; R = 384; S = 384; src = Wproj; dst = WprojT;
    r0 = (rem / 12) * 32; s0 = (rem % 12) * 32; perm = 1;
  } else if (bid < 1152) {   // W1 384x1536
    int rem = bid - 576; R = 384; S = 1536; src = W1; dst = W1T;
    r0 = (rem / 48) * 32; s0 = (rem % 48) * 32;
  } else {                   // W2 1536x384 (k-axis pih per 64-block)
    int rem = bid - 1152; R = 1536; S = 384; src = W2; dst = W2T;
    r0 = (rem / 12) * 32; s0 = (rem % 12) * 32; perm = 1;
  }
  __shared__ float t[32][33];
#pragma unroll
  for (int i = 0; i < 32; i += 8)
    t[ty + i][tx] = src[(size_t)(r0 + ty + i) * S + s0 + tx];
  __syncthreads();
  const int kk = r0 + tx;
  int kp = kk;
  if (perm) kp = (kk & ~63) | (((kk & 15) << 2) | ((kk >> 4) & 3));
#pragma unroll
  for (int i = 0; i < 32; i += 8)
    dst[(size_t)(s0 + ty + i) * R + kp] = f2bf(t[tx][ty + i]);
}

// ---------------------------------------------------------------------------
// LayerNorm (LN2): one wave per row of 384; 4 rows per block. bf16 output.
// ---------------------------------------------------------------------------
template <typename T>
__global__ __launch_bounds__(256) void ln_kernel(
    const T* __restrict__ x, const float* __restrict__ w,
    const float* __restrict__ b, ushort* __restrict__ out, int nrows) {
  int row  = blockIdx.x * 4 + (threadIdx.x >> 6);
  int lane = threadIdx.x & 63;
  if (row >= nrows) return;
  const T* xr = x + (size_t)row * Cdim;
  float v[6];
  float s = 0.f;
#pragma unroll
  for (int i = 0; i < 6; ++i) {
    if constexpr (sizeof(T) == 2) v[i] = bf2f(xr[lane + 64 * i]);
    else                          v[i] = xr[lane + 64 * i];
    s += v[i];
  }
#pragma unroll
  for (int off = 32; off > 0; off >>= 1) s += __shfl_xor(s, off, 64);
  float mean = s * (1.f / Cdim);
  float sq = 0.f;
#pragma unroll
  for (int i = 0; i < 6; ++i) { float d = v[i] - mean; sq += d * d; }
#pragma unroll
  for (int off = 32; off > 0; off >>= 1) sq += __shfl_xor(sq, off, 64);
  float rstd = rsqrtf(sq * (1.f / Cdim) + 1e-5f);
  ushort* orow = out + (size_t)row * Cdim;
#pragma unroll
  for (int i = 0; i < 6; ++i) {
    int c = lane + 64 * i;
    orow[c] = f2bf((v[i] - mean) * rstd * w[c] + b[c]);
  }
}

// ---------------------------------------------------------------------------
// bf16 MFMA GEMM: C[M,NN] = epi(A[M,KK] @ Bt[NN,KK]^T + bias). 128xBN tile,
// BK=64, 512-thread/8-wave blocks (R11: occupancy 17.7->30.9%, -6%).
// R18: NN,KK are TEMPLATE params + K-loop fully unrolled. R11 counters:
// VALUBusy 48% (20 us of 42.2) with epilogue accounting for only ~8 us ->
// the rest is per-iteration address math (runtime K forces v_mad_u64 per
// stage; rolled loop re-derives LDS addrs). With constexpr KK and unroll:
// k0*2 folds into global_load_lds' 13-bit imm (max 2944 B < 4096), row*KK
// becomes hoisted shifts, LDS buffer bases become constants.
// Counted-vmcnt pipeline unchanged:
//   stage(t+1 -> buf^1); vmcnt(LPT); barrier;   // tile t landed, t+1 in flight
//   ds_read+MFMA on buf; lgkmcnt(0); barrier.
// LPT = 4 (BN=128) or 3 (BN=64). LDS [buf][row][64], XOR chunk swizzle
// slot=(c&7)^(row&7); readers quad (half*4+g)^(lm&7) -> 2-way (free, m136).
// EPI: 1 = +bias+res(fp32) -> bf16 (proj -> x1)
//      2 = gelu -> bf16, per-64-block pih-permuted g (FFN1)
//      3 = QKV flat [M][1152], per-head pih-permuted dims
//      4 = +bias+res(bf16) -> fp32 (FFN2 -> out)
// XCD swizzle requires gridDim.y==128.
// ---------------------------------------------------------------------------
template <int EPI, int BN, int NN, int KK>
__global__ __launch_bounds__(512) void mfma_gemm(
    const ushort* __restrict__ A, const ushort* __restrict__ Bt,
    const float* __restrict__ bias, const void* __restrict__ res,
    void* __restrict__ Cout, void* __restrict__ C2, void* __restrict__ C3) {
  constexpr int WC  = BN / 2;   // wave col span
  constexpr int JN  = WC / 16;  // col frags per wave (4 or 2)
  constexpr int NBQ = BN / 64;  // B staging passes per thread (2 or 1)
  constexpr int nt  = KK >> 6;  // K-steps
  __shared__ ushort Als[2 * 128 * 64];
  __shared__ ushort Bls[2 * BN * 64];
  const int tid = threadIdx.x;

  // XCD-aware remap (requires gridDim.y == 128)
  const int lid = blockIdx.y * gridDim.x + blockIdx.x;
  const int xcd = lid & 7, idx = lid >> 3;
  const int by = xcd * 16 + (idx & 15);
  const int bx = idx >> 4;
  const int m0 = by * 128, n0 = bx * BN;

  const int lane = tid & 63;
  const int w    = tid >> 6;          // 0..7
  const int wr   = (w & 3) * 32;      // 32-row strip
  const int wc   = (w >> 2) * WC;     // col half
  const int lm   = lane & 15;
  const int g    = lane >> 4;
  const int rq   = g * 4;

  const int wub = (tid & ~63) * 8;  // wave-uniform ushort offset of lane 0

  f32x4 acc[2][JN] = {};

  // Per-thread staging base pointers (k0 = 0); unrolled stages add the
  // constant k0 so it folds into the load instruction's immediate offset.
  const ushort* gA0;
  const ushort* gA1;
  const ushort* gB0;
  const ushort* gB1;
  {
    const int ciA0 = tid, ciA1 = tid + 512;
    gA0 = A + (size_t)(m0 + (ciA0 >> 3)) * KK + ((ciA0 & 7) ^ ((ciA0 >> 3) & 7)) * 8;
    gA1 = A + (size_t)(m0 + (ciA1 >> 3)) * KK + ((ciA1 & 7) ^ ((ciA1 >> 3) & 7)) * 8;
    const int ciB0 = tid, ciB1 = tid + 512;
    gB0 = Bt + (size_t)(n0 + (ciB0 >> 3)) * KK + ((ciB0 & 7) ^ ((ciB0 >> 3) & 7)) * 8;
    if (NBQ == 2)
      gB1 = Bt + (size_t)(n0 + (ciB1 >> 3)) * KK + ((ciB1 & 7) ^ ((ciB1 >> 3) & 7)) * 8;
    else
      gB1 = gB0;  // unused
  }

  // Stage one BK=64 tile (compile-time k0) into LDS buffer `bf`.
  auto stage = [&](int k0, int bf) {
    ushort* Ab = Als + bf * (128 * 64);
    ushort* Bb = Bls + bf * (BN * 64);
    __builtin_amdgcn_global_load_lds(
        (const __attribute__((address_space(1))) uint*)(gA0 + k0),
        (__attribute__((address_space(3))) uint*)(Ab + wub), 16, 0, 0);
    __builtin_amdgcn_global_load_lds(
        (const __attribute__((address_space(1))) uint*)(gA1 + k0),
        (__attribute__((address_space(3))) uint*)(Ab + wub + 4096), 16, 0, 0);
    __builtin_amdgcn_global_load_lds(
        (const __attribute__((address_space(1))) uint*)(gB0 + k0),
        (__attribute__((address_space(3))) uint*)(Bb + wub), 16, 0, 0);
    if (NBQ == 2)
      __builtin_amdgcn_global_load_lds(
          (const __attribute__((address_space(1))) uint*)(gB1 + k0),
          (__attribute__((address_space(3))) uint*)(Bb + wub + 4096), 16, 0, 0);
  };

  stage(0, 0);

#pragma unroll
  for (int t = 0; t < nt; ++t) {
    const int cur = t & 1;
    if (t + 1 < nt) {
      stage((t + 1) * 64, cur ^ 1);
      // Wait only tile t's loads; the newest LPT (tile t+1) stay in flight.
      if constexpr (NBQ == 2)
        asm volatile("s_waitcnt vmcnt(4)" ::: "memory");
      else
        asm volatile("s_waitcnt vmcnt(3)" ::: "memory");
    } else {
      asm volatile("s_waitcnt vmcnt(0)" ::: "memory");
    }
    __builtin_amdgcn_sched_barrier(0);
    __builtin_amdgcn_s_barrier();      // everyone's tile-t loads landed
    __builtin_amdgcn_sched_barrier(0);

    const ushort* Ab = Als + cur * (128 * 64);
    const ushort* Bb = Bls + cur * (BN * 64);
#pragma unroll
    for (int half = 0; half < 2; ++half) {
      const int sl = ((half << 2) | g) ^ (lm & 7);  // swizzled chunk slot
      short8 af[2], bfr[JN];
#pragma unroll
      for (int i = 0; i < 2; ++i)
        af[i] = *(const short8*)&Ab[(wr + i * 16 + lm) * 64 + sl * 8];
#pragma unroll
      for (int j = 0; j < JN; ++j)
        bfr[j] = *(const short8*)&Bb[(wc + j * 16 + lm) * 64 + sl * 8];
      __builtin_amdgcn_s_setprio(1);
#pragma unroll
      for (int i = 0; i < 2; ++i)
#pragma unroll
        for (int j = 0; j < JN; ++j)
          acc[i][j] = __builtin_amdgcn_mfma_f32_16x16x32_bf16(af[i], bfr[j],
                                                              acc[i][j], 0, 0, 0);
      __builtin_amdgcn_s_setprio(0);
    }

    // All ds_reads retired; fence then barrier so next stage may overwrite.
    asm volatile("s_waitcnt lgkmcnt(0)" ::: "memory");
    __builtin_amdgcn_sched_barrier(0);
    __builtin_amdgcn_s_barrier();
    __builtin_amdgcn_sched_barrier(0);
  }

  float bb[JN];
#pragma unroll
  for (int j = 0; j < JN; ++j) bb[j] = bias[n0 + wc + j * 16 + lm];

#pragma unroll
  for (int i = 0; i < 2; ++i) {
#pragma unroll
    for (int r = 0; r < 4; ++r) {
      const int row = m0 + wr + i * 16 + rq + r;
      if constexpr (EPI == 1) {        // + fp32 residual -> bf16 out (true layout)
        const float* resrow = (const float*)res + (size_t)row * NN + n0 + wc;
        ushort* crow = (ushort*)Cout + (size_t)row * NN + n0 + wc;
#pragma unroll
        for (int j = 0; j < JN; ++j) {
          float rv = __builtin_nontemporal_load(resrow + j * 16 + lm);
          crow[j * 16 + lm] = f2bf(acc[i][j][r] + bb[j] + rv);
        }
      } else if constexpr (EPI == 4) { // + bf16 residual -> fp32 out
        const ushort* resrow = (const ushort*)res + (size_t)row * NN + n0 + wc;
        float* crow = (float*)Cout + (size_t)row * NN + n0 + wc;
#pragma unroll
        for (int j = 0; j < JN; ++j)
          crow[j * 16 + lm] = acc[i][j][r] + bb[j] + bf2f(resrow[j * 16 + lm]);
      } else if constexpr (EPI == 3) { // QKV flat, per-head pih perm (JN==4)
        // true col c = n0+wc+j*16+lm; stored at (n0+wc) + lm*4 + j.
        ushort* crow = (ushort*)Cout + (size_t)row * NN + n0 + wc + lm * 4;
        uint d0 = pk_bf16(acc[i][0][r] + bb[0], acc[i][1][r] + bb[1]);
        uint d1 = pk_bf16(acc[i][2][r] + bb[2], acc[i][3][r] + bb[3]);
        uint2 pkv; pkv.x = d0; pkv.y = d1;
        *(uint2*)crow = pkv;
      } else {                         // EPI == 2: gelu -> per-64-block pih g
        ushort* crow = (ushort*)Cout + (size_t)row * NN + n0 + wc + lm * 4;
        float g0 = gelu_fast(acc[i][0][r] + bb[0]);
        float g1 = gelu_fast(acc[i][1][r] + bb[1]);
        float g2 = gelu_fast(acc[i][2][r] + bb[2]);
        float g3 = gelu_fast(acc[i][3][r] + bb[3]);
        uint d0 = pk_bf16(g0, g1);
        uint d1 = pk_bf16(g2, g3);
        uint2 pkv; pkv.x = d0; pkv.y = d1;
        *(uint2*)crow = pkv;
      }
    }
  }
}

// ---------------------------------------------------------------------------
// MFMA flash attention on the flat QKV buffer [M][1152] (Q|K|V sections,
// head dims stored pih-permuted — Q,K identically so QK^T is invariant;
// V's permuted dims flow to Oc cols, matched by WprojT's k-perm).
// Block = (b*H+h, q-tile of 64 rows), 4 waves; wave w owns a 16-row Q strip.
// LDS stride 72 ushorts -> conflict-free frag reads. V transposed into LDS
// during staging. Output Oc bf16 [M][384] concat (stored-position order).
// ---------------------------------------------------------------------------
__global__ __launch_bounds__(256) void attn_kernel(
    const ushort* __restrict__ QKV, ushort* __restrict__ Oc) {
  __shared__ ushort Ks[64 * 72];     // [key][dim]
  __shared__ ushort Vt[64 * 72];     // [dim][key]
  __shared__ ushort Pl[4][16 * 72];  // per-wave P strip [row][key]
  const int bh = blockIdx.x, qt = blockIdx.y;
  const int b = bh / Hh, h = bh % Hh;
  const int tid = threadIdx.x;
  const int w = tid >> 6, lane = tid & 63;
  const int g = lane >> 4, n16 = lane & 15;

  const ushort* qrow =
      QKV + (size_t)(b * Tseq + qt * 64 + w * 16 + n16) * Nqkv + h * HSd;
  short8 qf0 = *(const short8*)(qrow + g * 8);
  short8 qf1 = *(const short8*)(qrow + 32 + g * 8);

  f32x4 oacc[4] = {};
  float m_r[4], l_r[4];
#pragma unroll
  for (int r = 0; r < 4; ++r) { m_r[r] = -1e30f; l_r[r] = 0.f; }

  const int t0 = qt * 64 + w * 16 + g * 4;

  const ushort* Ksrc = QKV + (size_t)b * Tseq * Nqkv + Cdim + h * HSd;
  const ushort* Vsrc = QKV + (size_t)b * Tseq * Nqkv + 2 * Cdim + h * HSd;

  for (int st = 0; st <= qt; ++st) {
    __syncthreads();
    for (int c = tid; c < 512; c += 256) {
      int kr = c >> 3, kc = (c & 7) * 8;
      *(uint4*)&Ks[kr * 72 + kc] =
          *(const uint4*)&Ksrc[(size_t)(st * 64 + kr) * Nqkv + kc];
      int vr = c & 63, vc = (c >> 6) * 8;
      uint4 vv = *(const uint4*)&Vsrc[(size_t)(st * 64 + vr) * Nqkv + vc];
      const ushort* pv = (const ushort*)&vv;
#pragma unroll
      for (int i = 0; i < 8; ++i) Vt[(vc + i) * 72 + vr] = pv[i];
    }
    __syncthreads();

    f32x4 s[4];
#pragma unroll
    for (int ct = 0; ct < 4; ++ct) {
      short8 kf0 = *(const short8*)&Ks[(ct * 16 + n16) * 72 + g * 8];
      short8 kf1 = *(const short8*)&Ks[(ct * 16 + n16) * 72 + 32 + g * 8];
      f32x4 z = {};
      z = __builtin_amdgcn_mfma_f32_16x16x32_bf16(qf0, kf0, z, 0, 0, 0);
      z = __builtin_amdgcn_mfma_f32_16x16x32_bf16(qf1, kf1, z, 0, 0, 0);
      s[ct] = z;
    }

#pragma unroll
    for (int ct = 0; ct < 4; ++ct) {
      const int s_col = st * 64 + ct * 16 + n16;
#pragma unroll
      for (int r = 0; r < 4; ++r) {
        float v = s[ct][r] * 0.125f;
        s[ct][r] = (s_col > t0 + r) ? -1e30f : v;
      }
    }

#pragma unroll
    for (int r = 0; r < 4; ++r) {
      float m = fmaxf(fmaxf(s[0][r], s[1][r]), fmaxf(s[2][r], s[3][r]));
      m = fmaxf(m, __shfl_xor(m, 1, 64));
      m = fmaxf(m, __shfl_xor(m, 2, 64));
      m = fmaxf(m, __shfl_xor(m, 4, 64));
      m = fmaxf(m, __shfl_xor(m, 8, 64));
      float mnew = fmaxf(m_r[r], m);
      float alpha = __expf(m_r[r] - mnew);
      m_r[r] = mnew;
      float ssum = 0.f;
#pragma unroll
      for (int ct = 0; ct < 4; ++ct) {
        float p = __expf(s[ct][r] - mnew);
        s[ct][r] = p;
        ssum += p;
      }
      ssum += __shfl_xor(ssum, 1, 64);
      ssum += __shfl_xor(ssum, 2, 64);
      ssum += __shfl_xor(ssum, 4, 64);
      ssum += __shfl_xor(ssum, 8, 64);
      l_r[r] = l_r[r] * alpha + ssum;
#pragma unroll
      for (int j = 0; j < 4; ++j) oacc[j][r] *= alpha;
    }

    ushort* pw = &Pl[w][0];
#pragma unroll
    for (int ct = 0; ct < 4; ++ct)
#pragma unroll
      for (int r = 0; r < 4; ++r)
        pw[(g * 4 + r) * 72 + ct * 16 + n16] = f2bf(s[ct][r]);

    short8 pf0 = *(const short8*)&pw[n16 * 72 + g * 8];
    short8 pf1 = *(const short8*)&pw[n16 * 72 + 32 + g * 8];
#pragma unroll
    for (int j = 0; j < 4; ++j) {
      short8 vf0 = *(const short8*)&Vt[(j * 16 + n16) * 72 + g * 8];
      short8 vf1 = *(const short8*)&Vt[(j * 16 + n16) * 72 + 32 + g * 8];
      oacc[j] = __builtin_amdgcn_mfma_f32_16x16x32_bf16(pf0, vf0, oacc[j], 0, 0, 0);
      oacc[j] = __builtin_amdgcn_mfma_f32_16x16x32_bf16(pf1, vf1, oacc[j], 0, 0, 0);
    }
  }

  float inv[4];
#pragma unroll
  for (int r = 0; r < 4; ++r) inv[r] = 1.f / l_r[r];
  ushort* orow = Oc + ((size_t)(b * Tseq + qt * 64 + w * 16)) * Cdim + h * HSd;
#pragma unroll
  for (int j = 0; j < 4; ++j)
#pragma unroll
    for (int r = 0; r < 4; ++r)
      orow[(size_t)(g * 4 + r) * Cdim + j * 16 + n16] = f2bf(oacc[j][r] * inv[r]);
}

// ---------------------------------------------------------------------------
extern "C" void kernel_launch(void* const* d_in, const int* in_sizes, int n_in,
                              void* d_out, int out_size, void* d_ws, size_t ws_size,
                              hipStream_t stream) {
  const float* x      = (const float*)d_in[0];
  const float* ln1_w  = (const float*)d_in[1];
  const float* ln1_b  = (const float*)d_in[2];
  const float* Wq     = (const float*)d_in[3];
  const float* bq     = (const float*)d_in[4];
  const float* Wk     = (const float*)d_in[5];
  const float* bk     = (const float*)d_in[6];
  const float* Wv     = (const float*)d_in[7];
  const float* bv     = (const float*)d_in[8];
  const float* Wproj  = (const float*)d_in[9];
  const float* bproj  = (const float*)d_in[10];
  const float* ln2_w  = (const float*)d_in[11];
  const float* ln2_b  = (const float*)d_in[12];
  const float* W1     = (const float*)d_in[13];
  const float* b1     = (const float*)d_in[14];
  const float* W2     = (const float*)d_in[15];
  const float* b2     = (const float*)d_in[16];
  float* out = (float*)d_out;

  // Workspace layout (~110 MB). QKV is one flat [M][1152] bf16 buffer;
  // x1 aliases it (QKV dead after attn; proj writes x1 afterwards).
  char* p = (char*)d_ws;
  ushort* h     = (ushort*)p;  p += (size_t)Mrows * Cdim * 2;   // reused as h2
  ushort* QKV   = (ushort*)p;  p += (size_t)Mrows * Nqkv * 2;   // x1 aliases
  ushort* Oc    = (ushort*)p;  p += (size_t)Mrows * Cdim * 2;
  ushort* g     = (ushort*)p;  p += (size_t)Mrows * Cffn * 2;
  ushort* WqkvT = (ushort*)p;  p += (size_t)Nqkv * Cdim * 2;
  ushort* WprojT= (ushort*)p;  p += (size_t)Cdim * Cdim * 2;
  ushort* W1T   = (ushort*)p;  p += (size_t)Cffn * Cdim * 2;
  ushort* W2T   = (ushort*)p;  p += (size_t)Cdim * Cffn * 2;
  float*  bqkv  = (float*)p;   p += (size_t)Nqkv * 4;
  ushort* h2 = h;
  ushort* x1 = QKV;

  dim3 blk(256), blk512(512);

  // 0. Fused weight prep + LN1 (one launch)
  prep_kernel<<<dim3(1733 + Mrows / 4), blk, 0, stream>>>(
      Wq, Wk, Wv, Wproj, W1, W2, bq, bk, bv, x, ln1_w, ln1_b,
      WqkvT, WprojT, W1T, W2T, bqkv, h);

  // 1. QKV fused GEMM -> flat [M][1152], per-head pih-permuted dims
  mfma_gemm<3, 128, Nqkv, Cdim><<<dim3(Nqkv / 128, Mrows / 128), blk512, 0, stream>>>(
      h, WqkvT, bqkv, nullptr, QKV, nullptr, nullptr);

  // 2. MFMA flash attention -> Oc (bf16, concat layout)
  attn_kernel<<<dim3(Bsz * Hh, 4), blk, 0, stream>>>(QKV, Oc);

  // 3. x1 = x + Oc @ Wproj + bproj -> bf16 (skinny N: BN=64)
  mfma_gemm<1, 64, Cdim, Cdim><<<dim3(Cdim / 64, Mrows / 128), blk512, 0, stream>>>(
      Oc, WprojT, bproj, x, x1, nullptr, nullptr);

  // 4. LN2 -> h2 (bf16, reads bf16 x1)
  ln_kernel<ushort><<<dim3(Mrows / 4), blk, 0, stream>>>(x1, ln2_w, ln2_b, h2, Mrows);

  // 5. g = gelu(h2 @ W1 + b1), per-64-block pih-permuted layout (bf16)
  mfma_gemm<2, 128, Cffn, Cdim><<<dim3(Cffn / 128, Mrows / 128), blk512, 0, stream>>>(
      h2, W1T, b1, nullptr, g, nullptr, nullptr);

  // 6. out = x1 + g @ W2 + b2 -> fp32 (bf16 residual; W2T pih-matched)
  mfma_gemm<4, 64, Cdim, Cffn><<<dim3(Cdim / 64, Mrows / 128), blk512, 0, stream>>>(
      g, W2T, b2, x1, out, nullptr, nullptr);
}

// Round 13
// 229.904 us; speedup vs baseline: 1.0366x; 1.0366x over previous
//
#include <hip/hip_runtime.h>
#include <math.h>

// Problem constants
constexpr int Bsz  = 64;
constexpr int Tseq = 256;
constexpr int Cdim = 384;
constexpr int Hh   = 6;
constexpr int HSd  = 64;
constexpr int Mrows = Bsz * Tseq;        // 16384
constexpr int Cffn  = 4 * Cdim;          // 1536
constexpr int Nqkv  = 3 * Cdim;          // 1152

typedef __attribute__((ext_vector_type(8))) short short8;  // 8 bf16 = 4 VGPRs
typedef __attribute__((ext_vector_type(4))) float f32x4;

// fp32 -> bf16 round-to-nearest-even
__device__ __forceinline__ ushort f2bf(float x) {
  union { float f; uint u; } a; a.f = x;
  uint r = a.u + 0x7fffu + ((a.u >> 16) & 1u);
  return (ushort)(r >> 16);
}
__device__ __forceinline__ float bf2f(ushort u) {
  union { uint u; float f; } a; a.u = ((uint)u) << 16;
  return a.f;
}
// Pack 2 f32 -> 2 bf16 (RNE) in one instruction (T12 recipe, no builtin).
__device__ __forceinline__ uint pk_bf16(float lo, float hi) {
  uint r;
  asm("v_cvt_pk_bf16_f32 %0, %1, %2" : "=v"(r) : "v"(lo), "v"(hi));
  return r;
}

// Fast GELU (tanh form): ~3e-4 max error vs exact-erf, ~8 VALU ops vs ~25.
__device__ __forceinline__ float gelu_fast(float x) {
  float t = x * x;
  float u = x * fmaf(0.044715f, t, 1.0f);
  float e = fminf(1.5957691216f * u, 80.f);
  float z = __expf(e);
  return x * (z / (1.0f + z));
}

// ---------------------------------------------------------------------------
// Fused prep + LN1, one launch (R10 win). Blocks 0..1727 = 32x32 transpose
// tiles; 1728..1732 bias concat; 1733..5828 = LN1 rows (4 rows per block).
// pih(c) = (c & ~63) + (c&15)*4 + ((c>>4)&3) k-permutation applied to
// Wproj k-axis (matches QKV EPI=3 store) and W2 k-axis (matches FFN1 EPI=2
// store). Per-64-block only (row-wide perm broke store coalescing, R5).
// ---------------------------------------------------------------------------
__global__ __launch_bounds__(256) void prep_kernel(
    const float* __restrict__ Wq, const float* __restrict__ Wk,
    const float* __restrict__ Wv, const float* __restrict__ Wproj,
    const float* __restrict__ W1, const float* __restrict__ W2,
    const float* __restrict__ bq, const float* __restrict__ bk,
    const float* __restrict__ bv,
    const float* __restrict__ x, const float* __restrict__ ln1_w,
    const float* __restrict__ ln1_b,
    ushort* __restrict__ WqkvT, ushort* __restrict__ WprojT,
    ushort* __restrict__ W1T, ushort* __restrict__ W2T,
    float* __restrict__ bqkv, ushort* __restrict__ hOut) {
  const int bid = blockIdx.x;
  if (bid >= 1733) {  // -------- LN1: 4 rows per block --------
    const int row  = (bid - 1733) * 4 + (threadIdx.x >> 6);
    const int lane = threadIdx.x & 63;
    if (row >= Mrows) return;
    const float* xr = x + (size_t)row * Cdim;
    float v[6];
    float s = 0.f;
#pragma unroll
    for (int i = 0; i < 6; ++i) { v[i] = xr[lane + 64 * i]; s += v[i]; }
#pragma unroll
    for (int off = 32; off > 0; off >>= 1) s += __shfl_xor(s, off, 64);
    float mean = s * (1.f / Cdim);
    float sq = 0.f;
#pragma unroll
    for (int i = 0; i < 6; ++i) { float d = v[i] - mean; sq += d * d; }
#pragma unroll
    for (int off = 32; off > 0; off >>= 1) sq += __shfl_xor(sq, off, 64);
    float rstd = rsqrtf(sq * (1.f / Cdim) + 1e-5f);
    ushort* orow = hOut + (size_t)row * Cdim;
#pragma unroll
    for (int i = 0; i < 6; ++i) {
      int c = lane + 64 * i;
      orow[c] = f2bf((v[i] - mean) * rstd * ln1_w[c] + ln1_b[c]);
    }
    return;
  }
  if (bid >= 1728) {  // bias concat
    int i = (bid - 1728) * 256 + threadIdx.x;
    if (i < Nqkv)
      bqkv[i] = (i < 384) ? bq[i] : (i < 768) ? bk[i - 384] : bv[i - 768];
    return;
  }
  const int tx = threadIdx.x & 31, ty = threadIdx.x >> 5;  // 32 x 8
  const float* src; ushort* dst; int R, S, r0, s0, perm = 0;
  if (bid < 432) {           // Wq/Wk/Wv: [6][384][64] each -> rows of WqkvT
    int which = bid / 144, rem = bid % 144;
    const float* W = (which == 0) ? Wq : (which == 1) ? Wk : Wv;
    int bz = rem / 24, t = rem % 24;
    R = 384; S = 64;
    src = W + (size_t)bz * R * S;
    dst = WqkvT + (size_t)which * 384 * 384 + (size_t)bz * R * S;
    r0 = (t >> 1) * 32; s0 = (t & 1) * 32;
  } else if (bid < 576) {    // Wproj 384x384 (k-axis pih per 64-block)
    int rem = bid - 432; R = 384; S = 384; src = Wproj; dst = WprojT;
    r0 = (rem / 12) * 32; s0 = (rem % 12) * 32; perm = 1;
  } else if (bid < 1152) {   // W1 384x1536
    int rem = bid - 576; R = 384; S = 1536; src = W1; dst = W1T;
    r0 = (rem / 48) * 32; s0 = (rem % 48) * 32;
  } else {                   // W2 1536x384 (k-axis pih per 64-block)
    int rem = bid - 1152; R = 1536; S = 384; src = W2; dst = W2T;
    r0 = (rem / 12) * 32; s0 = (rem % 12) * 32; perm = 1;
  }
  __shared__ float t[32][33];
#pragma unroll
  for (int i = 0; i < 32; i += 8)
    t[ty + i][tx] = src[(size_t)(r0 + ty + i) * S + s0 + tx];
  __syncthreads();
  const int kk = r0 + tx;
  int kp = kk;
  if (perm) kp = (kk & ~63) | (((kk & 15) << 2) | ((kk >> 4) & 3));
#pragma unroll
  for (int i = 0; i < 32; i += 8)
    dst[(size_t)(s0 + ty + i) * R + kp] = f2bf(t[tx][ty + i]);
}

// ---------------------------------------------------------------------------
// LayerNorm (LN2): one wave per row of 384; 4 rows per block. bf16 output.
// ---------------------------------------------------------------------------
template <typename T>
__global__ __launch_bounds__(256) void ln_kernel(
    const T* __restrict__ x, const float* __restrict__ w,
    const float* __restrict__ b, ushort* __restrict__ out, int nrows) {
  int row  = blockIdx.x * 4 + (threadIdx.x >> 6);
  int lane = threadIdx.x & 63;
  if (row >= nrows) return;
  const T* xr = x + (size_t)row * Cdim;
  float v[6];
  float s = 0.f;
#pragma unroll
  for (int i = 0; i < 6; ++i) {
    if constexpr (sizeof(T) == 2) v[i] = bf2f(xr[lane + 64 * i]);
    else                          v[i] = xr[lane + 64 * i];
    s += v[i];
  }
#pragma unroll
  for (int off = 32; off > 0; off >>= 1) s += __shfl_xor(s, off, 64);
  float mean = s * (1.f / Cdim);
  float sq = 0.f;
#pragma unroll
  for (int i = 0; i < 6; ++i) { float d = v[i] - mean; sq += d * d; }
#pragma unroll
  for (int off = 32; off > 0; off >>= 1) sq += __shfl_xor(sq, off, 64);
  float rstd = rsqrtf(sq * (1.f / Cdim) + 1e-5f);
  ushort* orow = out + (size_t)row * Cdim;
#pragma unroll
  for (int i = 0; i < 6; ++i) {
    int c = lane + 64 * i;
    orow[c] = f2bf((v[i] - mean) * rstd * w[c] + b[c]);
  }
}

// ---------------------------------------------------------------------------
// bf16 MFMA GEMM: C[M,NN] = epi(A[M,KK] @ Bt[NN,KK]^T + bias). 128xBN tile,
// BK=64, 512-thread/8-wave blocks (R11: best, 42.2 us FFN1 / 236.1 total).
// R19: keep R11's ROLLED loop (R12's full unroll regressed 42.2->48.3 us
// despite VALUBusy 48->37% — rigid sched_barrier-fenced copies removed the
// compiler's cross-iteration scheduling slack; m141 family). Keep only the
// two R12 elements that are pure wins:
//   (a) NN,KK template params: constexpr epilogue strides + strength-reduced
//       address multiplies;
//   (b) precomputed per-thread staging base pointers, bumped +64 elems per
//       stage call (4x 64-bit adds/iter vs full (m0+row)*K recompute).
// Counted-vmcnt pipeline unchanged:
//   stage(t+1 -> buf^1); vmcnt(LPT); barrier;   // tile t landed, t+1 in flight
//   ds_read+MFMA on buf; lgkmcnt(0); barrier.
// LPT = 4 (BN=128) or 3 (BN=64). LDS [buf][row][64], XOR chunk swizzle
// slot=(c&7)^(row&7); readers quad (half*4+g)^(lm&7) -> 2-way (free, m136).
// EPI: 1 = +bias+res(fp32) -> bf16 (proj -> x1)
//      2 = gelu -> bf16, per-64-block pih-permuted g (FFN1)
//      3 = QKV flat [M][1152], per-head pih-permuted dims
//      4 = +bias+res(bf16) -> fp32 (FFN2 -> out)
// XCD swizzle requires gridDim.y==128.
// ---------------------------------------------------------------------------
template <int EPI, int BN, int NN, int KK>
__global__ __launch_bounds__(512) void mfma_gemm(
    const ushort* __restrict__ A, const ushort* __restrict__ Bt,
    const float* __restrict__ bias, const void* __restrict__ res,
    void* __restrict__ Cout, void* __restrict__ C2, void* __restrict__ C3) {
  constexpr int WC  = BN / 2;   // wave col span
  constexpr int JN  = WC / 16;  // col frags per wave (4 or 2)
  constexpr int NBQ = BN / 64;  // B staging passes per thread (2 or 1)
  constexpr int nt  = KK >> 6;  // K-steps
  __shared__ ushort Als[2 * 128 * 64];
  __shared__ ushort Bls[2 * BN * 64];
  const int tid = threadIdx.x;

  // XCD-aware remap (requires gridDim.y == 128)
  const int lid = blockIdx.y * gridDim.x + blockIdx.x;
  const int xcd = lid & 7, idx = lid >> 3;
  const int by = xcd * 16 + (idx & 15);
  const int bx = idx >> 4;
  const int m0 = by * 128, n0 = bx * BN;

  const int lane = tid & 63;
  const int w    = tid >> 6;          // 0..7
  const int wr   = (w & 3) * 32;      // 32-row strip
  const int wc   = (w >> 2) * WC;     // col half
  const int lm   = lane & 15;
  const int g    = lane >> 4;
  const int rq   = g * 4;

  const int wub = (tid & ~63) * 8;  // wave-uniform ushort offset of lane 0

  f32x4 acc[2][JN] = {};

  // Per-thread staging pointers, always pointing at the NEXT tile to stage;
  // bumped +64 elements after each stage call.
  const ushort* gA0;
  const ushort* gA1;
  const ushort* gB0;
  const ushort* gB1;
  {
    const int ciA0 = tid, ciA1 = tid + 512;
    gA0 = A + (size_t)(m0 + (ciA0 >> 3)) * KK + ((ciA0 & 7) ^ ((ciA0 >> 3) & 7)) * 8;
    gA1 = A + (size_t)(m0 + (ciA1 >> 3)) * KK + ((ciA1 & 7) ^ ((ciA1 >> 3) & 7)) * 8;
    const int ciB0 = tid, ciB1 = tid + 512;
    gB0 = Bt + (size_t)(n0 + (ciB0 >> 3)) * KK + ((ciB0 & 7) ^ ((ciB0 >> 3) & 7)) * 8;
    gB1 = (NBQ == 2)
        ? Bt + (size_t)(n0 + (ciB1 >> 3)) * KK + ((ciB1 & 7) ^ ((ciB1 >> 3) & 7)) * 8
        : gB0;  // unused when NBQ==1
  }

  // Stage one BK=64 tile into LDS buffer `bf`, then advance pointers.
  auto stage = [&](int bf) {
    ushort* Ab = Als + bf * (128 * 64);
    ushort* Bb = Bls + bf * (BN * 64);
    __builtin_amdgcn_global_load_lds(
        (const __attribute__((address_space(1))) uint*)gA0,
        (__attribute__((address_space(3))) uint*)(Ab + wub), 16, 0, 0);
    __builtin_amdgcn_global_load_lds(
        (const __attribute__((address_space(1))) uint*)gA1,
        (__attribute__((address_space(3))) uint*)(Ab + wub + 4096), 16, 0, 0);
    __builtin_amdgcn_global_load_lds(
        (const __attribute__((address_space(1))) uint*)gB0,
        (__attribute__((address_space(3))) uint*)(Bb + wub), 16, 0, 0);
    if (NBQ == 2)
      __builtin_amdgcn_global_load_lds(
          (const __attribute__((address_space(1))) uint*)gB1,
          (__attribute__((address_space(3))) uint*)(Bb + wub + 4096), 16, 0, 0);
    gA0 += 64; gA1 += 64; gB0 += 64;
    if (NBQ == 2) gB1 += 64;
  };

  stage(0);

  for (int t = 0; t < nt; ++t) {
    const int cur = t & 1;
    if (t + 1 < nt) {
      stage(cur ^ 1);
      // Wait only tile t's loads; the newest LPT (tile t+1) stay in flight.
      if constexpr (NBQ == 2)
        asm volatile("s_waitcnt vmcnt(4)" ::: "memory");
      else
        asm volatile("s_waitcnt vmcnt(3)" ::: "memory");
    } else {
      asm volatile("s_waitcnt vmcnt(0)" ::: "memory");
    }
    __builtin_amdgcn_sched_barrier(0);
    __builtin_amdgcn_s_barrier();      // everyone's tile-t loads landed
    __builtin_amdgcn_sched_barrier(0);

    const ushort* Ab = Als + cur * (128 * 64);
    const ushort* Bb = Bls + cur * (BN * 64);
#pragma unroll
    for (int half = 0; half < 2; ++half) {
      const int sl = ((half << 2) | g) ^ (lm & 7);  // swizzled chunk slot
      short8 af[2], bfr[JN];
#pragma unroll
      for (int i = 0; i < 2; ++i)
        af[i] = *(const short8*)&Ab[(wr + i * 16 + lm) * 64 + sl * 8];
#pragma unroll
      for (int j = 0; j < JN; ++j)
        bfr[j] = *(const short8*)&Bb[(wc + j * 16 + lm) * 64 + sl * 8];
      __builtin_amdgcn_s_setprio(1);
#pragma unroll
      for (int i = 0; i < 2; ++i)
#pragma unroll
        for (int j = 0; j < JN; ++j)
          acc[i][j] = __builtin_amdgcn_mfma_f32_16x16x32_bf16(af[i], bfr[j],
                                                              acc[i][j], 0, 0, 0);
      __builtin_amdgcn_s_setprio(0);
    }

    // All ds_reads retired; fence then barrier so next stage may overwrite.
    asm volatile("s_waitcnt lgkmcnt(0)" ::: "memory");
    __builtin_amdgcn_sched_barrier(0);
    __builtin_amdgcn_s_barrier();
    __builtin_amdgcn_sched_barrier(0);
  }

  float bb[JN];
#pragma unroll
  for (int j = 0; j < JN; ++j) bb[j] = bias[n0 + wc + j * 16 + lm];

#pragma unroll
  for (int i = 0; i < 2; ++i) {
#pragma unroll
    for (int r = 0; r < 4; ++r) {
      const int row = m0 + wr + i * 16 + rq + r;
      if constexpr (EPI == 1) {        // + fp32 residual -> bf16 out (true layout)
        const float* resrow = (const float*)res + (size_t)row * NN + n0 + wc;
        ushort* crow = (ushort*)Cout + (size_t)row * NN + n0 + wc;
#pragma unroll
        for (int j = 0; j < JN; ++j) {
          float rv = __builtin_nontemporal_load(resrow + j * 16 + lm);
          crow[j * 16 + lm] = f2bf(acc[i][j][r] + bb[j] + rv);
        }
      } else if constexpr (EPI == 4) { // + bf16 residual -> fp32 out
        const ushort* resrow = (const ushort*)res + (size_t)row * NN + n0 + wc;
        float* crow = (float*)Cout + (size_t)row * NN + n0 + wc;
#pragma unroll
        for (int j = 0; j < JN; ++j)
          crow[j * 16 + lm] = acc[i][j][r] + bb[j] + bf2f(resrow[j * 16 + lm]);
      } else if constexpr (EPI == 3) { // QKV flat, per-head pih perm (JN==4)
        // true col c = n0+wc+j*16+lm; stored at (n0+wc) + lm*4 + j.
        ushort* crow = (ushort*)Cout + (size_t)row * NN + n0 + wc + lm * 4;
        uint d0 = pk_bf16(acc[i][0][r] + bb[0], acc[i][1][r] + bb[1]);
        uint d1 = pk_bf16(acc[i][2][r] + bb[2], acc[i][3][r] + bb[3]);
        uint2 pkv; pkv.x = d0; pkv.y = d1;
        *(uint2*)crow = pkv;
      } else {                         // EPI == 2: gelu -> per-64-block pih g
        ushort* crow = (ushort*)Cout + (size_t)row * NN + n0 + wc + lm * 4;
        float g0 = gelu_fast(acc[i][0][r] + bb[0]);
        float g1 = gelu_fast(acc[i][1][r] + bb[1]);
        float g2 = gelu_fast(acc[i][2][r] + bb[2]);
        float g3 = gelu_fast(acc[i][3][r] + bb[3]);
        uint d0 = pk_bf16(g0, g1);
        uint d1 = pk_bf16(g2, g3);
        uint2 pkv; pkv.x = d0; pkv.y = d1;
        *(uint2*)crow = pkv;
      }
    }
  }
}

// ---------------------------------------------------------------------------
// MFMA flash attention on the flat QKV buffer [M][1152] (Q|K|V sections,
// head dims stored pih-permuted — Q,K identically so QK^T is invariant;
// V's permuted dims flow to Oc cols, matched by WprojT's k-perm).
// Block = (b*H+h, q-tile of 64 rows), 4 waves; wave w owns a 16-row Q strip.
// LDS stride 72 ushorts -> conflict-free frag reads. V transposed into LDS
// during staging. Output Oc bf16 [M][384] concat (stored-position order).
// ---------------------------------------------------------------------------
__global__ __launch_bounds__(256) void attn_kernel(
    const ushort* __restrict__ QKV, ushort* __restrict__ Oc) {
  __shared__ ushort Ks[64 * 72];     // [key][dim]
  __shared__ ushort Vt[64 * 72];     // [dim][key]
  __shared__ ushort Pl[4][16 * 72];  // per-wave P strip [row][key]
  const int bh = blockIdx.x, qt = blockIdx.y;
  const int b = bh / Hh, h = bh % Hh;
  const int tid = threadIdx.x;
  const int w = tid >> 6, lane = tid & 63;
  const int g = lane >> 4, n16 = lane & 15;

  const ushort* qrow =
      QKV + (size_t)(b * Tseq + qt * 64 + w * 16 + n16) * Nqkv + h * HSd;
  short8 qf0 = *(const short8*)(qrow + g * 8);
  short8 qf1 = *(const short8*)(qrow + 32 + g * 8);

  f32x4 oacc[4] = {};
  float m_r[4], l_r[4];
#pragma unroll
  for (int r = 0; r < 4; ++r) { m_r[r] = -1e30f; l_r[r] = 0.f; }

  const int t0 = qt * 64 + w * 16 + g * 4;

  const ushort* Ksrc = QKV + (size_t)b * Tseq * Nqkv + Cdim + h * HSd;
  const ushort* Vsrc = QKV + (size_t)b * Tseq * Nqkv + 2 * Cdim + h * HSd;

  for (int st = 0; st <= qt; ++st) {
    __syncthreads();
    for (int c = tid; c < 512; c += 256) {
      int kr = c >> 3, kc = (c & 7) * 8;
      *(uint4*)&Ks[kr * 72 + kc] =
          *(const uint4*)&Ksrc[(size_t)(st * 64 + kr) * Nqkv + kc];
      int vr = c & 63, vc = (c >> 6) * 8;
      uint4 vv = *(const uint4*)&Vsrc[(size_t)(st * 64 + vr) * Nqkv + vc];
      const ushort* pv = (const ushort*)&vv;
#pragma unroll
      for (int i = 0; i < 8; ++i) Vt[(vc + i) * 72 + vr] = pv[i];
    }
    __syncthreads();

    f32x4 s[4];
#pragma unroll
    for (int ct = 0; ct < 4; ++ct) {
      short8 kf0 = *(const short8*)&Ks[(ct * 16 + n16) * 72 + g * 8];
      short8 kf1 = *(const short8*)&Ks[(ct * 16 + n16) * 72 + 32 + g * 8];
      f32x4 z = {};
      z = __builtin_amdgcn_mfma_f32_16x16x32_bf16(qf0, kf0, z, 0, 0, 0);
      z = __builtin_amdgcn_mfma_f32_16x16x32_bf16(qf1, kf1, z, 0, 0, 0);
      s[ct] = z;
    }

#pragma unroll
    for (int ct = 0; ct < 4; ++ct) {
      const int s_col = st * 64 + ct * 16 + n16;
#pragma unroll
      for (int r = 0; r < 4; ++r) {
        float v = s[ct][r] * 0.125f;
        s[ct][r] = (s_col > t0 + r) ? -1e30f : v;
      }
    }

#pragma unroll
    for (int r = 0; r < 4; ++r) {
      float m = fmaxf(fmaxf(s[0][r], s[1][r]), fmaxf(s[2][r], s[3][r]));
      m = fmaxf(m, __shfl_xor(m, 1, 64));
      m = fmaxf(m, __shfl_xor(m, 2, 64));
      m = fmaxf(m, __shfl_xor(m, 4, 64));
      m = fmaxf(m, __shfl_xor(m, 8, 64));
      float mnew = fmaxf(m_r[r], m);
      float alpha = __expf(m_r[r] - mnew);
      m_r[r] = mnew;
      float ssum = 0.f;
#pragma unroll
      for (int ct = 0; ct < 4; ++ct) {
        float p = __expf(s[ct][r] - mnew);
        s[ct][r] = p;
        ssum += p;
      }
      ssum += __shfl_xor(ssum, 1, 64);
      ssum += __shfl_xor(ssum, 2, 64);
      ssum += __shfl_xor(ssum, 4, 64);
      ssum += __shfl_xor(ssum, 8, 64);
      l_r[r] = l_r[r] * alpha + ssum;
#pragma unroll
      for (int j = 0; j < 4; ++j) oacc[j][r] *= alpha;
    }

    ushort* pw = &Pl[w][0];
#pragma unroll
    for (int ct = 0; ct < 4; ++ct)
#pragma unroll
      for (int r = 0; r < 4; ++r)
        pw[(g * 4 + r) * 72 + ct * 16 + n16] = f2bf(s[ct][r]);

    short8 pf0 = *(const short8*)&pw[n16 * 72 + g * 8];
    short8 pf1 = *(const short8*)&pw[n16 * 72 + 32 + g * 8];
#pragma unroll
    for (int j = 0; j < 4; ++j) {
      short8 vf0 = *(const short8*)&Vt[(j * 16 + n16) * 72 + g * 8];
      short8 vf1 = *(const short8*)&Vt[(j * 16 + n16) * 72 + 32 + g * 8];
      oacc[j] = __builtin_amdgcn_mfma_f32_16x16x32_bf16(pf0, vf0, oacc[j], 0, 0, 0);
      oacc[j] = __builtin_amdgcn_mfma_f32_16x16x32_bf16(pf1, vf1, oacc[j], 0, 0, 0);
    }
  }

  float inv[4];
#pragma unroll
  for (int r = 0; r < 4; ++r) inv[r] = 1.f / l_r[r];
  ushort* orow = Oc + ((size_t)(b * Tseq + qt * 64 + w * 16)) * Cdim + h * HSd;
#pragma unroll
  for (int j = 0; j < 4; ++j)
#pragma unroll
    for (int r = 0; r < 4; ++r)
      orow[(size_t)(g * 4 + r) * Cdim + j * 16 + n16] = f2bf(oacc[j][r] * inv[r]);
}

// ---------------------------------------------------------------------------
extern "C" void kernel_launch(void* const* d_in, const int* in_sizes, int n_in,
                              void* d_out, int out_size, void* d_ws, size_t ws_size,
                              hipStream_t stream) {
  const float* x      = (const float*)d_in[0];
  const float* ln1_w  = (const float*)d_in[1];
  const float* ln1_b  = (const float*)d_in[2];
  const float* Wq     = (const float*)d_in[3];
  const float* bq     = (const float*)d_in[4];
  const float* Wk     = (const float*)d_in[5];
  const float* bk     = (const float*)d_in[6];
  const float* Wv     = (const float*)d_in[7];
  const float* bv     = (const float*)d_in[8];
  const float* Wproj  = (const float*)d_in[9];
  const float* bproj  = (const float*)d_in[10];
  const float* ln2_w  = (const float*)d_in[11];
  const float* ln2_b  = (const float*)d_in[12];
  const float* W1     = (const float*)d_in[13];
  const float* b1     = (const float*)d_in[14];
  const float* W2     = (const float*)d_in[15];
  const float* b2     = (const float*)d_in[16];
  float* out = (float*)d_out;

  // Workspace layout (~110 MB). QKV is one flat [M][1152] bf16 buffer;
  // x1 aliases it (QKV dead after attn; proj writes x1 afterwards).
  char* p = (char*)d_ws;
  ushort* h     = (ushort*)p;  p += (size_t)Mrows * Cdim * 2;   // reused as h2
  ushort* QKV   = (ushort*)p;  p += (size_t)Mrows * Nqkv * 2;   // x1 aliases
  ushort* Oc    = (ushort*)p;  p += (size_t)Mrows * Cdim * 2;
  ushort* g     = (ushort*)p;  p += (size_t)Mrows * Cffn * 2;
  ushort* WqkvT = (ushort*)p;  p += (size_t)Nqkv * Cdim * 2;
  ushort* WprojT= (ushort*)p;  p += (size_t)Cdim * Cdim * 2;
  ushort* W1T   = (ushort*)p;  p += (size_t)Cffn * Cdim * 2;
  ushort* W2T   = (ushort*)p;  p += (size_t)Cdim * Cffn * 2;
  float*  bqkv  = (float*)p;   p += (size_t)Nqkv * 4;
  ushort* h2 = h;
  ushort* x1 = QKV;

  dim3 blk(256), blk512(512);

  // 0. Fused weight prep + LN1 (one launch)
  prep_kernel<<<dim3(1733 + Mrows / 4), blk, 0, stream>>>(
      Wq, Wk, Wv, Wproj, W1, W2, bq, bk, bv, x, ln1_w, ln1_b,
      WqkvT, WprojT, W1T, W2T, bqkv, h);

  // 1. QKV fused GEMM -> flat [M][1152], per-head pih-permuted dims
  mfma_gemm<3, 128, Nqkv, Cdim><<<dim3(Nqkv / 128, Mrows / 128), blk512, 0, stream>>>(
      h, WqkvT, bqkv, nullptr, QKV, nullptr, nullptr);

  // 2. MFMA flash attention -> Oc (bf16, concat layout)
  attn_kernel<<<dim3(Bsz * Hh, 4), blk, 0, stream>>>(QKV, Oc);

  // 3. x1 = x + Oc @ Wproj + bproj -> bf16 (skinny N: BN=64)
  mfma_gemm<1, 64, Cdim, Cdim><<<dim3(Cdim / 64, Mrows / 128), blk512, 0, stream>>>(
      Oc, WprojT, bproj, x, x1, nullptr, nullptr);

  // 4. LN2 -> h2 (bf16, reads bf16 x1)
  ln_kernel<ushort><<<dim3(Mrows / 4), blk, 0, stream>>>(x1, ln2_w, ln2_b, h2, Mrows);

  // 5. g = gelu(h2 @ W1 + b1), per-64-block pih-permuted layout (bf16)
  mfma_gemm<2, 128, Cffn, Cdim><<<dim3(Cffn / 128, Mrows / 128), blk512, 0, stream>>>(
      h2, W1T, b1, nullptr, g, nullptr, nullptr);

  // 6. out = x1 + g @ W2 + b2 -> fp32 (bf16 residual; W2T pih-matched)
  mfma_gemm<4, 64, Cdim, Cffn><<<dim3(Cdim / 64, Mrows / 128), blk512, 0, stream>>>(
      g, W2T, b2, x1, out, nullptr, nullptr);
}